// Round 1
// 302.144 us; speedup vs baseline: 1.0005x; 1.0005x over previous
//
#include <hip/hip_runtime.h>
#include <hip/hip_bf16.h>

#define D 1024

typedef unsigned int u32;
typedef __attribute__((ext_vector_type(4))) unsigned int u32x4;

__device__ __forceinline__ float bflo(u32 u) { return __uint_as_float(u << 16); }
__device__ __forceinline__ float bfhi(u32 u) { return __uint_as_float(u & 0xffff0000u); }
__device__ __forceinline__ float bf1(const void* p, int j) {
    unsigned short s = ((const unsigned short*)p)[j];
    return __uint_as_float(((u32)s) << 16);
}

__device__ __forceinline__ float waveReduceSum(float v) {
#pragma unroll
    for (int off = 32; off > 0; off >>= 1) v += __shfl_xor(v, off, 64);
    return v;
}

// Per-block dtype probe: wave 0 inspects the first 64 words of h_t and
// checks whether their LOW halves decode to sane bf16 exponents.
// Deterministic on identical data -> consistent across blocks.
__device__ __forceinline__ int probeDtype(const u32* __restrict__ htw) {
    __shared__ int sflag;
    if (threadIdx.x < 64) {
        u32 w = htw[threadIdx.x];
        u32 e = (w >> 7) & 0xFF;
        unsigned long long m = __ballot(e >= 100 && e <= 126);
        if (threadIdx.x == 0) sflag = (__popcll(m) >= 56) ? 1 : 0;
    }
    __syncthreads();
    return sflag;
}

// q[j] = dot(W0[j,:], h_t) + b0[j]   (1024 waves, one row each)
// Fused: per-block dtype probe; block 0 zeroes e_s/L and publishes flag.
__global__ __launch_bounds__(256) void k_q(const void* __restrict__ W0,
                                           const void* __restrict__ ht,
                                           const void* __restrict__ b0,
                                           float* __restrict__ q,
                                           int* __restrict__ flag,
                                           float* __restrict__ L,
                                           float* __restrict__ e_s) {
    int isBf16 = probeDtype((const u32*)ht);
    if (blockIdx.x == 0) {
        for (int k = threadIdx.x; k < D; k += 256) e_s[k] = 0.f;
        if (threadIdx.x == 0) { *L = 0.f; *flag = isBf16; }
    }

    int wid = threadIdx.x >> 6, lane = threadIdx.x & 63;
    int j = blockIdx.x * 4 + wid;
    float s = 0.f;
    if (isBf16) {
        const u32x4* wrow = (const u32x4*)((const __hip_bfloat16*)W0 + (size_t)j * D);
        const u32x4* hv = (const u32x4*)ht;
#pragma unroll
        for (int half = 0; half < 2; ++half) {
            u32x4 a = wrow[half * 64 + lane];
            u32x4 b = hv[half * 64 + lane];
#pragma unroll
            for (int t = 0; t < 4; ++t) {
                s += bflo(a[t]) * bflo(b[t]);
                s += bfhi(a[t]) * bfhi(b[t]);
            }
        }
    } else {
        const float4* wrow = (const float4*)((const float*)W0 + (size_t)j * D);
        const float4* hv = (const float4*)ht;
#pragma unroll
        for (int t = 0; t < 4; ++t) {
            float4 a = wrow[t * 64 + lane];
            float4 b = hv[t * 64 + lane];
            s += a.x * b.x + a.y * b.y + a.z * b.z + a.w * b.w;
        }
    }
    s = waveReduceSum(s);
    if (lane == 0) {
        float bias = isBf16 ? bf1(b0, j) : ((const float*)b0)[j];
        q[j] = s + bias;
    }
}

// Fused single pass over H: w_i = exp(exp(H_i . q)), accumulate sum w_i and
// sum w_i * H_i. Two rows per iteration (ILP pipeline): independent tree
// dots, interleaved shuffle reduces, shared accumulator.
__global__ __launch_bounds__(512) void k_pass(const int* __restrict__ flag,
                                              const void* __restrict__ Hm,
                                              const float* __restrict__ q,
                                              float* __restrict__ e_s,
                                              float* __restrict__ Lp,
                                              int N, int totalWaves) {
    __shared__ float lacc[8][D];
    __shared__ float ll[8];
    int wid = threadIdx.x >> 6, lane = threadIdx.x & 63;
    int gw = blockIdx.x * 8 + wid;
    int isBf16 = *flag;

    // column indices this lane owns (same mapping for qr and h)
    int col[16];
    if (isBf16) {
#pragma unroll
        for (int j = 0; j < 8; ++j) {
            col[j] = lane * 8 + j;
            col[8 + j] = 512 + lane * 8 + j;
        }
    } else {
#pragma unroll
        for (int t = 0; t < 4; ++t)
#pragma unroll
            for (int u = 0; u < 4; ++u) col[t * 4 + u] = t * 256 + lane * 4 + u;
    }
    float qr[16];
#pragma unroll
    for (int j = 0; j < 16; ++j) qr[j] = q[col[j]];

    float l = 0.f;
    float acc[16];
#pragma unroll
    for (int j = 0; j < 16; ++j) acc[j] = 0.f;

    const int TW = totalWaves;
    for (int r = gw; r < N; r += 2 * TW) {
        int r2 = r + TW;
        int has2 = r2 < N;
        int rr2 = has2 ? r2 : r;  // safe duplicate load on tail

        float h0[16], h1[16];
        if (isBf16) {
            const u32x4* hr0 = (const u32x4*)((const __hip_bfloat16*)Hm + (size_t)r * D);
            const u32x4* hr1 = (const u32x4*)((const __hip_bfloat16*)Hm + (size_t)rr2 * D);
            u32x4 a0 = hr0[lane], b0v = hr0[64 + lane];
            u32x4 a1 = hr1[lane], b1v = hr1[64 + lane];
#pragma unroll
            for (int t = 0; t < 4; ++t) {
                h0[2 * t] = bflo(a0[t]);     h0[2 * t + 1] = bfhi(a0[t]);
                h0[8 + 2 * t] = bflo(b0v[t]); h0[8 + 2 * t + 1] = bfhi(b0v[t]);
                h1[2 * t] = bflo(a1[t]);     h1[2 * t + 1] = bfhi(a1[t]);
                h1[8 + 2 * t] = bflo(b1v[t]); h1[8 + 2 * t + 1] = bfhi(b1v[t]);
            }
        } else {
            const float4* hr0 = (const float4*)((const float*)Hm + (size_t)r * D);
            const float4* hr1 = (const float4*)((const float*)Hm + (size_t)rr2 * D);
#pragma unroll
            for (int t = 0; t < 4; ++t) {
                float4 a = hr0[t * 64 + lane];
                h0[t * 4 + 0] = a.x; h0[t * 4 + 1] = a.y;
                h0[t * 4 + 2] = a.z; h0[t * 4 + 3] = a.w;
            }
#pragma unroll
            for (int t = 0; t < 4; ++t) {
                float4 a = hr1[t * 64 + lane];
                h1[t * 4 + 0] = a.x; h1[t * 4 + 1] = a.y;
                h1[t * 4 + 2] = a.z; h1[t * 4 + 3] = a.w;
            }
        }

        // tree dots: 4 independent partials per row, chain depth 4 FMA + 2 adds
        float s00 = 0.f, s01 = 0.f, s02 = 0.f, s03 = 0.f;
        float s10 = 0.f, s11 = 0.f, s12 = 0.f, s13 = 0.f;
#pragma unroll
        for (int j = 0; j < 4; ++j) {
            s00 += h0[j] * qr[j];           s01 += h0[4 + j] * qr[4 + j];
            s02 += h0[8 + j] * qr[8 + j];   s03 += h0[12 + j] * qr[12 + j];
            s10 += h1[j] * qr[j];           s11 += h1[4 + j] * qr[4 + j];
            s12 += h1[8 + j] * qr[8 + j];   s13 += h1[12 + j] * qr[12 + j];
        }
        float d0 = (s00 + s01) + (s02 + s03);
        float d1 = (s10 + s11) + (s12 + s13);

        // interleaved reduces: the two 6-step shuffle chains overlap in latency
#pragma unroll
        for (int off = 32; off > 0; off >>= 1) {
            d0 += __shfl_xor(d0, off, 64);
            d1 += __shfl_xor(d1, off, 64);
        }

        float p0 = __expf(__expf(d0));
        float p1 = has2 ? __expf(__expf(d1)) : 0.f;
        l += p0 + p1;
#pragma unroll
        for (int j = 0; j < 16; ++j) acc[j] += p0 * h0[j] + p1 * h1[j];
    }

    // block combine: 8 waves -> LDS -> one atomic per element
#pragma unroll
    for (int j = 0; j < 16; ++j) lacc[wid][col[j]] = acc[j];
    if (lane == 0) ll[wid] = l;
    __syncthreads();
    for (int k = threadIdx.x; k < D; k += 512) {
        float s = 0.f;
#pragma unroll
        for (int w = 0; w < 8; ++w) s += lacc[w][k];
        atomicAdd(&e_s[k], s);
    }
    if (threadIdx.x == 0) {
        float s = 0.f;
#pragma unroll
        for (int w = 0; w < 8; ++w) s += ll[w];
        atomicAdd(Lp, s);
    }
}

// out[j] = tanh(dot(W1[j,:], e_s)/L + b1[j] + dot(W2[j,:], h_t) + b2[j])
__global__ __launch_bounds__(256) void k_out(const int* __restrict__ flag,
                                             const void* __restrict__ W1,
                                             const void* __restrict__ b1,
                                             const void* __restrict__ W2,
                                             const void* __restrict__ b2,
                                             const void* __restrict__ ht,
                                             const float* __restrict__ e_s,
                                             const float* __restrict__ Lp,
                                             void* __restrict__ out) {
    int wid = threadIdx.x >> 6, lane = threadIdx.x & 63;
    int j = blockIdx.x * 4 + wid;
    int isBf16 = *flag;
    float s1 = 0.f, s2 = 0.f;
    if (isBf16) {
        const u32x4* w1r = (const u32x4*)((const __hip_bfloat16*)W1 + (size_t)j * D);
        const u32x4* w2r = (const u32x4*)((const __hip_bfloat16*)W2 + (size_t)j * D);
        const u32x4* hv = (const u32x4*)ht;
        int c0 = lane * 8;
#pragma unroll
        for (int half = 0; half < 2; ++half) {
            u32x4 a = w1r[half * 64 + lane];
            u32x4 b = w2r[half * 64 + lane];
            u32x4 hh = hv[half * 64 + lane];
            const float4* ev = (const float4*)(e_s + half * 512 + c0);
            float4 ea = ev[0], eb = ev[1];
            float e[8] = {ea.x, ea.y, ea.z, ea.w, eb.x, eb.y, eb.z, eb.w};
#pragma unroll
            for (int t = 0; t < 4; ++t) {
                s1 += bflo(a[t]) * e[2 * t] + bfhi(a[t]) * e[2 * t + 1];
                s2 += bflo(b[t]) * bflo(hh[t]) + bfhi(b[t]) * bfhi(hh[t]);
            }
        }
    } else {
        const float4* w1r = (const float4*)((const float*)W1 + (size_t)j * D);
        const float4* w2r = (const float4*)((const float*)W2 + (size_t)j * D);
        const float4* hv = (const float4*)ht;
        const float4* ev = (const float4*)e_s;
#pragma unroll
        for (int t = 0; t < 4; ++t) {
            float4 a = w1r[t * 64 + lane];
            float4 b = w2r[t * 64 + lane];
            float4 hh = hv[t * 64 + lane];
            float4 ee = ev[t * 64 + lane];
            s1 += a.x * ee.x + a.y * ee.y + a.z * ee.z + a.w * ee.w;
            s2 += b.x * hh.x + b.y * hh.y + b.z * hh.z + b.w * hh.w;
        }
    }
    s1 = waveReduceSum(s1);
    s2 = waveReduceSum(s2);
    if (lane == 0) {
        float bias1 = isBf16 ? bf1(b1, j) : ((const float*)b1)[j];
        float bias2 = isBf16 ? bf1(b2, j) : ((const float*)b2)[j];
        float r = tanhf(s1 / (*Lp) + bias1 + s2 + bias2);
        if (isBf16) ((__hip_bfloat16*)out)[j] = __float2bfloat16(r);
        else        ((float*)out)[j] = r;
    }
}

extern "C" void kernel_launch(void* const* d_in, const int* in_sizes, int n_in,
                              void* d_out, int out_size, void* d_ws, size_t ws_size,
                              hipStream_t stream) {
    const void* H  = d_in[0];
    const void* ht = d_in[1];
    const void* W0 = d_in[2];
    const void* b0 = d_in[3];
    const void* W1 = d_in[4];
    const void* b1 = d_in[5];
    const void* W2 = d_in[6];
    const void* b2 = d_in[7];
    int N = in_sizes[0] / D;

    float* wsf  = (float*)d_ws;
    int*   flag = (int*)wsf;          // [1]
    float* L    = wsf + 1;            // [1]
    float* q    = wsf + 64;           // [1024]
    float* e_s  = wsf + 64 + 1024;    // [1024] (16B aligned offset)

    const int B = 512;  // k_pass blocks, 8 waves each

    k_q<<<256, 256, 0, stream>>>(W0, ht, b0, q, flag, L, e_s);
    k_pass<<<B, 512, 0, stream>>>(flag, H, q, e_s, L, N, B * 8);
    k_out<<<256, 256, 0, stream>>>(flag, W1, b1, W2, b2, ht, e_s, L, d_out);
}